// Round 11
// baseline (518.022 us; speedup 1.0000x reference)
//
#include <hip/hip_runtime.h>
#include <hip/hip_bf16.h>

#define NN 8192
#define FIN 256
#define FOUT 64
#define L2E 1.4426950408889634f
#define PADK 40   // LDS k-stride in shorts (32 data + 8 pad -> even bank spread)

typedef __attribute__((ext_vector_type(8))) short short8;
typedef __attribute__((ext_vector_type(4))) float f32x4;
typedef __attribute__((ext_vector_type(4))) int   iv4;

// Barrier with LDS-only drain: leaves vmcnt (global prefetch) in flight.
#define BAR() do { \
  __asm__ __volatile__("s_waitcnt lgkmcnt(0)" ::: "memory"); \
  __builtin_amdgcn_s_barrier(); \
  __asm__ __volatile__("" ::: "memory"); \
} while (0)

__device__ __forceinline__ unsigned short f2bf(float x){
  unsigned u = __float_as_uint(x);
  u += 0x7FFFu + ((u >> 16) & 1u);      // RTNE
  return (unsigned short)(u >> 16);
}

// k_prep: Wh = h@W fp32; fs/fd pre-scaled by log2(e); WhT bf16 [64][8192];
// global max of fdL via uint atomicMax(+64 bias, monotone for positives).
__global__ __launch_bounds__(256) void k_prep(const float* __restrict__ h,
    const float* __restrict__ W, const float* __restrict__ a,
    unsigned short* __restrict__ WhT, float* __restrict__ fs,
    float* __restrict__ fd, unsigned* __restrict__ gmax_u){
  __shared__ float Ws[128*64];   // 32 KB: half of W (k-tiled)
  __shared__ float hs[8][128];   // 4 KB: 8 rows, k-half
  const int t = threadIdx.x, l = t & 63, wv = t >> 6;
  const int rb = blockIdx.x * 8;            // 8 rows per block, 2 per wave
  float acc0 = 0.f, acc1 = 0.f;
  for (int half = 0; half < 2; ++half){
    if (half) __syncthreads();
    for (int i = t; i < 2048; i += 256)
      ((float4*)Ws)[i] = ((const float4*)W)[half*2048 + i];
    {
      int rr = t >> 5, cc = t & 31;
      ((float4*)&hs[rr][0])[cc] =
          *(const float4*)(h + (size_t)(rb+rr)*FIN + half*128 + cc*4);
    }
    __syncthreads();
    #pragma unroll 8
    for (int k = 0; k < 128; ++k){
      float wval = Ws[k*64 + l];             // lane l = output feature
      acc0 = fmaf(hs[wv*2+0][k], wval, acc0);
      acc1 = fmaf(hs[wv*2+1][k], wval, acc1);
    }
  }
  const int r0 = rb + wv*2, r1 = r0 + 1;
  float a1 = a[l], a2 = a[64 + l];
  float p0 = acc0*a1, q0 = acc0*a2, p1 = acc1*a1, q1 = acc1*a2;
  #pragma unroll
  for (int m = 1; m < 64; m <<= 1){
    p0 += __shfl_xor(p0, m); q0 += __shfl_xor(q0, m);
    p1 += __shfl_xor(p1, m); q1 += __shfl_xor(q1, m);
  }
  if (l == 0){
    fs[r0] = p0*L2E; fs[r1] = p1*L2E; fd[r0] = q0*L2E; fd[r1] = q1*L2E;
    atomicMax(gmax_u, __float_as_uint(q0*L2E + 64.0f));
    atomicMax(gmax_u, __float_as_uint(q1*L2E + 64.0f));
  }
  WhT[(size_t)l*NN + r0] = f2bf(acc0);
  WhT[(size_t)l*NN + r1] = f2bf(acc1);
}

// ---- k_attn (R9 structure, nt REMOVED): block = 64 i-rows x 1024-j kchunk.
// WhT+fd staged in LDS per K-step; adj = 2-deep register prefetch with PLAIN
// loads. R11 theory: __builtin_nontemporal_load defeated cross-instruction
// cache-line reuse (each 128B adj line is consumed by two successive load
// instructions) -> 2x DRAM traffic. 512MB/93.4us = 5.5 TB/s says the R9
// kernel streamed at ~87% efficiency on DOUBLE the bytes.
struct ABuf { iv4 a0, a1; };   // adj, 8 ints

__device__ __forceinline__ void load_adj(ABuf& b, const int* __restrict__ adj,
                                         unsigned a_off, int s){
  const iv4* p = (const iv4*)(adj + a_off + s*32);
  b.a0 = p[0];     // plain loads: lines stay cached across the pair
  b.a1 = p[1];
}

__device__ __forceinline__ void attn_math(const ABuf& ab, f32x4 fv0, f32x4 fv1,
    short8 w0, short8 w1, short8 w2, short8 w3,
    float fsrL, float mL, f32x4* acc, float& s0, float& s1){
  const int   av[8] = {ab.a0.x,ab.a0.y,ab.a0.z,ab.a0.w, ab.a1.x,ab.a1.y,ab.a1.z,ab.a1.w};
  const float fv[8] = {fv0[0],fv0[1],fv0[2],fv0[3], fv1[0],fv1[1],fv1[2],fv1[3]};
  float w[8];
  #pragma unroll
  for (int j = 0; j < 8; ++j){
    float x  = fsrL + fv[j];                      // log2 domain
    float tt = fmaxf(x, 0.2f*x);                  // leaky_relu (scale-invariant)
    float e  = __builtin_amdgcn_exp2f(tt - mL);   // v_exp_f32
    w[j] = (av[j] != 0) ? e : 0.0f;               // adj mask
  }
  s0 += (w[0]+w[2]) + (w[4]+w[6]);
  s1 += (w[1]+w[3]) + (w[5]+w[7]);
  short8 af;
  __hip_bfloat162* afp = (__hip_bfloat162*)&af;
  #pragma unroll
  for (int j = 0; j < 4; ++j)
    afp[j] = __float22bfloat162_rn(make_float2(w[2*j], w[2*j+1]));  // v_cvt_pk_bf16_f32
  acc[0] = __builtin_amdgcn_mfma_f32_16x16x32_bf16(af, w0, acc[0], 0,0,0);
  acc[1] = __builtin_amdgcn_mfma_f32_16x16x32_bf16(af, w1, acc[1], 0,0,0);
  acc[2] = __builtin_amdgcn_mfma_f32_16x16x32_bf16(af, w2, acc[2], 0,0,0);
  acc[3] = __builtin_amdgcn_mfma_f32_16x16x32_bf16(af, w3, acc[3], 0,0,0);
}

// Verified layouts (m89/m120): A[m=lane&15][k=(lane>>4)*8+j],
// B[k=(lane>>4)*8+j][n=lane&15], C col=lane&15 row=(lane>>4)*4+reg.
__global__ __launch_bounds__(256, 4) void k_attn(const int* __restrict__ adj,
    const unsigned short* __restrict__ WhT, const float* __restrict__ fs,
    const float* __restrict__ fd, const unsigned* __restrict__ gmax_u,
    float* __restrict__ acc_out, float* __restrict__ s_out){
  __shared__ unsigned short bslab[2][64*PADK];   // [buf][n][k]
  __shared__ float fslab[2][32];
  const int t = threadIdx.x, l = t & 63, wv = t >> 6;
  const int g = blockIdx.x & 127;        // 128 groups of 64 i-rows
  const int kchunk = blockIdx.x >> 7;    // 8 k-splits of 1024 j
  const int row = l & 15, quad = l >> 4;
  const int ibase = g*64 + wv*16;
  const int irow  = ibase + row;
  const float gmaxL = __uint_as_float(*gmax_u) - 64.0f;
  const float fsrL  = fs[irow];
  const float xL    = fsrL + gmaxL;
  const float mL    = fmaxf(xL, 0.2f*xL);  // row-max upper bound (leaky monotone)

  const unsigned jbase = (unsigned)kchunk*1024u;
  const unsigned a_off = (unsigned)irow*8192u + jbase + (unsigned)quad*8u;
  const unsigned sg_off = (unsigned)l*8192u + jbase + (unsigned)wv*8u;
  const int      sl_off = l*PADK + wv*8;
  const int      qsh    = quad*8;

  f32x4 acc[4];
  #pragma unroll
  for (int nb = 0; nb < 4; ++nb) acc[nb] = (f32x4){0.f,0.f,0.f,0.f};

  // prologue: stage step 0 into buf 0
  {
    short8 v = *(const short8*)(WhT + sg_off);
    *(short8*)&bslab[0][sl_off] = v;
    if (t < 32) fslab[0][t] = fd[jbase + t];
  }
  ABuf ab0, ab1;
  load_adj(ab0, adj, a_off, 0);
  load_adj(ab1, adj, a_off, 1);

  float s0 = 0.f, s1 = 0.f;
  short8 nw; float nf = 0.f;

  #pragma unroll 1
  for (int s = 0; s < 32; s += 2){
    // ---- even sub-step: consume buf0/ab0, stage s+1 -> buf1
    BAR();
    nw = *(const short8*)(WhT + sg_off + (s+1)*32);
    if (t < 32) nf = fd[jbase + (s+1)*32 + t];
    {
      f32x4 fv0 = *(const f32x4*)&fslab[0][qsh];
      f32x4 fv1 = *(const f32x4*)&fslab[0][qsh + 4];
      short8 w0 = *(const short8*)&bslab[0][( 0 + row)*PADK + qsh];
      short8 w1 = *(const short8*)&bslab[0][(16 + row)*PADK + qsh];
      short8 w2 = *(const short8*)&bslab[0][(32 + row)*PADK + qsh];
      short8 w3 = *(const short8*)&bslab[0][(48 + row)*PADK + qsh];
      attn_math(ab0, fv0, fv1, w0, w1, w2, w3, fsrL, mL, acc, s0, s1);
    }
    if (s + 2 < 32) load_adj(ab0, adj, a_off, s + 2);
    *(short8*)&bslab[1][sl_off] = nw;
    if (t < 32) fslab[1][t] = nf;

    // ---- odd sub-step: consume buf1/ab1, stage s+2 -> buf0
    BAR();
    if (s + 2 < 32){
      nw = *(const short8*)(WhT + sg_off + (s+2)*32);
      if (t < 32) nf = fd[jbase + (s+2)*32 + t];
    }
    {
      f32x4 fv0 = *(const f32x4*)&fslab[1][qsh];
      f32x4 fv1 = *(const f32x4*)&fslab[1][qsh + 4];
      short8 w0 = *(const short8*)&bslab[1][( 0 + row)*PADK + qsh];
      short8 w1 = *(const short8*)&bslab[1][(16 + row)*PADK + qsh];
      short8 w2 = *(const short8*)&bslab[1][(32 + row)*PADK + qsh];
      short8 w3 = *(const short8*)&bslab[1][(48 + row)*PADK + qsh];
      attn_math(ab1, fv0, fv1, w0, w1, w2, w3, fsrL, mL, acc, s0, s1);
    }
    if (s + 3 < 32) load_adj(ab1, adj, a_off, s + 3);
    if (s + 2 < 32){
      *(short8*)&bslab[0][sl_off] = nw;
      if (t < 32) fslab[0][t] = nf;
    }
  }

  float sacc = s0 + s1;
  sacc += __shfl_xor(sacc, 16);
  sacc += __shfl_xor(sacc, 32);
  if (l < 16) s_out[kchunk*NN + ibase + l] = sacc;
  float* op = acc_out + ((size_t)kchunk*NN + ibase)*FOUT;
  #pragma unroll
  for (int nb = 0; nb < 4; ++nb)
    #pragma unroll
    for (int r = 0; r < 4; ++r)
      op[(quad*4 + r)*FOUT + nb*16 + row] = acc[nb][r];
}

// ---- k_out: combine 8 split-K partials, normalize, ELU.
__global__ __launch_bounds__(256) void k_out(const float* __restrict__ acc,
    const float* __restrict__ s, float* __restrict__ out){
  const int idx = blockIdx.x*256 + threadIdx.x;   // 524288 total
  const int i = idx >> 6;
  float num = 0.f, den = 0.f;
  #pragma unroll
  for (int ks = 0; ks < 8; ++ks){
    num += acc[idx + (size_t)ks*(NN*FOUT)];
    den += s[i + ks*NN];
  }
  float x = num / den;
  out[idx] = (x > 0.f) ? x : (__expf(x) - 1.0f);
}

extern "C" void kernel_launch(void* const* d_in, const int* in_sizes, int n_in,
                              void* d_out, int out_size, void* d_ws, size_t ws_size,
                              hipStream_t stream){
  const float* h   = (const float*)d_in[0];
  const int*   adj = (const int*)d_in[1];
  const float* W   = (const float*)d_in[2];
  const float* a   = (const float*)d_in[3];
  char* ws = (char*)d_ws;
  // ws: [0,1M) WhT | 1M fs | +32K fd | +64K gmax | [2M,18M) acc x8 | [20M,+256K) s x8
  unsigned short* WhT = (unsigned short*)ws;
  float*    fs     = (float*)(ws + (1u<<20));
  float*    fd     = (float*)(ws + (1u<<20) + 32768);
  unsigned* gmax_u = (unsigned*)(ws + (1u<<20) + 65536);
  float*    acc    = (float*)(ws + (2u<<20));
  float*    s_ws   = (float*)(ws + (20u<<20));

  (void)hipMemsetAsync(gmax_u, 0, 4, stream);
  k_prep<<<1024, 256, 0, stream>>>(h, W, a, WhT, fs, fd, gmax_u);
  k_attn<<<1024, 256, 0, stream>>>(adj, WhT, fs, fd, gmax_u, acc, s_ws);
  k_out<<<2048, 256, 0, stream>>>(acc, s_ws, (float*)d_out);
}

// Round 12
// 495.673 us; speedup vs baseline: 1.0451x; 1.0451x over previous
//
#include <hip/hip_runtime.h>
#include <hip/hip_bf16.h>

#define NN 8192
#define FIN 256
#define FOUT 64
#define L2E 1.4426950408889634f
#define PADK 40   // LDS k-stride in shorts (32 data + 8 pad -> even bank spread)

typedef __attribute__((ext_vector_type(8))) short short8;
typedef __attribute__((ext_vector_type(4))) float f32x4;
typedef __attribute__((ext_vector_type(4))) int   iv4;

// Barrier with LDS-only drain: leaves vmcnt (global prefetch) in flight.
#define BAR() do { \
  __asm__ __volatile__("s_waitcnt lgkmcnt(0)" ::: "memory"); \
  __builtin_amdgcn_s_barrier(); \
  __asm__ __volatile__("" ::: "memory"); \
} while (0)

__device__ __forceinline__ unsigned short f2bf(float x){
  unsigned u = __float_as_uint(x);
  u += 0x7FFFu + ((u >> 16) & 1u);      // RTNE
  return (unsigned short)(u >> 16);
}

// ---- k_pm: heterogeneous fused kernel.
// blocks [0,1024): prep — Wh=h@W fp32, fs/fd (log2e-scaled), WhT bf16, gmax.
// blocks [1024,3072): adj -> bitmask via __ballot. One wave = one adj row,
// perfectly linear 256B/instr loads, 8 in flight, NO LDS / NO barriers
// (R10's converter was barrier-latency-bound; this one is a pure stream).
__global__ __launch_bounds__(256) void k_pm(const float* __restrict__ h,
    const float* __restrict__ W, const float* __restrict__ a,
    const int* __restrict__ adj, unsigned short* __restrict__ WhT,
    float* __restrict__ fs, float* __restrict__ fd,
    unsigned* __restrict__ gmax_u, unsigned* __restrict__ mask){
  const int bid = blockIdx.x, t = threadIdx.x;
  const int l = t & 63, wv = t >> 6;
  if (bid < 1024){
    __shared__ float Ws[128*64];   // 32 KB: half of W (k-tiled)
    __shared__ float hs[8][128];
    const int rb = bid * 8;                 // 8 rows per block, 2 per wave
    float acc0 = 0.f, acc1 = 0.f;
    for (int half = 0; half < 2; ++half){
      if (half) __syncthreads();
      for (int i = t; i < 2048; i += 256)
        ((float4*)Ws)[i] = ((const float4*)W)[half*2048 + i];
      {
        int rr = t >> 5, cc = t & 31;
        ((float4*)&hs[rr][0])[cc] =
            *(const float4*)(h + (size_t)(rb+rr)*FIN + half*128 + cc*4);
      }
      __syncthreads();
      #pragma unroll 8
      for (int k = 0; k < 128; ++k){
        float wval = Ws[k*64 + l];           // lane l = output feature
        acc0 = fmaf(hs[wv*2+0][k], wval, acc0);
        acc1 = fmaf(hs[wv*2+1][k], wval, acc1);
      }
    }
    const int r0 = rb + wv*2, r1 = r0 + 1;
    float a1 = a[l], a2 = a[64 + l];
    float p0 = acc0*a1, q0 = acc0*a2, p1 = acc1*a1, q1 = acc1*a2;
    #pragma unroll
    for (int m = 1; m < 64; m <<= 1){
      p0 += __shfl_xor(p0, m); q0 += __shfl_xor(q0, m);
      p1 += __shfl_xor(p1, m); q1 += __shfl_xor(q1, m);
    }
    if (l == 0){
      fs[r0] = p0*L2E; fs[r1] = p1*L2E; fd[r0] = q0*L2E; fd[r1] = q1*L2E;
      atomicMax(gmax_u, __float_as_uint(q0*L2E + 64.0f));
      atomicMax(gmax_u, __float_as_uint(q1*L2E + 64.0f));
    }
    WhT[(size_t)l*NN + r0] = f2bf(acc0);
    WhT[(size_t)l*NN + r1] = f2bf(acc1);
  } else {
    // converter: wave handles one row (8192 ints, 32 KB, linear).
    const unsigned rowid = (unsigned)(bid - 1024)*4u + (unsigned)wv;  // 0..8191
    const int* __restrict__ ap = adj + (size_t)rowid*8192u + (unsigned)l;
    unsigned* __restrict__ mp = mask + rowid*256u;
    #pragma unroll 1
    for (int i = 0; i < 128; i += 8){
      int v0 = __builtin_nontemporal_load(ap + (i+0)*64);
      int v1 = __builtin_nontemporal_load(ap + (i+1)*64);
      int v2 = __builtin_nontemporal_load(ap + (i+2)*64);
      int v3 = __builtin_nontemporal_load(ap + (i+3)*64);
      int v4 = __builtin_nontemporal_load(ap + (i+4)*64);
      int v5 = __builtin_nontemporal_load(ap + (i+5)*64);
      int v6 = __builtin_nontemporal_load(ap + (i+6)*64);
      int v7 = __builtin_nontemporal_load(ap + (i+7)*64);
      unsigned long long b0 = __ballot(v0 != 0), b1 = __ballot(v1 != 0);
      unsigned long long b2 = __ballot(v2 != 0), b3 = __ballot(v3 != 0);
      unsigned long long b4 = __ballot(v4 != 0), b5 = __ballot(v5 != 0);
      unsigned long long b6 = __ballot(v6 != 0), b7 = __ballot(v7 != 0);
      // bit k of ballot = lane k = j offset k within the 64-j span ✓
      if (l == 0){
        mp[(i+0)*2] = (unsigned)b0; mp[(i+1)*2] = (unsigned)b1;
        mp[(i+2)*2] = (unsigned)b2; mp[(i+3)*2] = (unsigned)b3;
        mp[(i+4)*2] = (unsigned)b4; mp[(i+5)*2] = (unsigned)b5;
        mp[(i+6)*2] = (unsigned)b6; mp[(i+7)*2] = (unsigned)b7;
      }
      if (l == 32){
        mp[(i+0)*2+1] = (unsigned)(b0>>32); mp[(i+1)*2+1] = (unsigned)(b1>>32);
        mp[(i+2)*2+1] = (unsigned)(b2>>32); mp[(i+3)*2+1] = (unsigned)(b3>>32);
        mp[(i+4)*2+1] = (unsigned)(b4>>32); mp[(i+5)*2+1] = (unsigned)(b5>>32);
        mp[(i+6)*2+1] = (unsigned)(b6>>32); mp[(i+7)*2+1] = (unsigned)(b7>>32);
      }
    }
  }
}

// ---- k_attn (R10-verified): block = 64 i-rows x 1024-j kchunk. WhT+fd staged
// in LDS; adj via bitmask (1 word / 32 j, L2-resident).
__device__ __forceinline__ void attn_math(unsigned mbits, f32x4 fv0, f32x4 fv1,
    short8 w0, short8 w1, short8 w2, short8 w3,
    float fsrL, float mL, f32x4* acc, float& s0, float& s1){
  const float fv[8] = {fv0[0],fv0[1],fv0[2],fv0[3], fv1[0],fv1[1],fv1[2],fv1[3]};
  float w[8];
  #pragma unroll
  for (int j = 0; j < 8; ++j){
    float x  = fsrL + fv[j];                      // log2 domain
    float tt = fmaxf(x, 0.2f*x);                  // leaky_relu (scale-invariant)
    float e  = __builtin_amdgcn_exp2f(tt - mL);   // v_exp_f32
    w[j] = (mbits & (1u << j)) ? e : 0.0f;        // adj bit
  }
  s0 += (w[0]+w[2]) + (w[4]+w[6]);
  s1 += (w[1]+w[3]) + (w[5]+w[7]);
  short8 af;
  __hip_bfloat162* afp = (__hip_bfloat162*)&af;
  #pragma unroll
  for (int j = 0; j < 4; ++j)
    afp[j] = __float22bfloat162_rn(make_float2(w[2*j], w[2*j+1]));  // v_cvt_pk_bf16_f32
  acc[0] = __builtin_amdgcn_mfma_f32_16x16x32_bf16(af, w0, acc[0], 0,0,0);
  acc[1] = __builtin_amdgcn_mfma_f32_16x16x32_bf16(af, w1, acc[1], 0,0,0);
  acc[2] = __builtin_amdgcn_mfma_f32_16x16x32_bf16(af, w2, acc[2], 0,0,0);
  acc[3] = __builtin_amdgcn_mfma_f32_16x16x32_bf16(af, w3, acc[3], 0,0,0);
}

// Verified layouts (m89/m120): A[m=lane&15][k=(lane>>4)*8+j],
// B[k=(lane>>4)*8+j][n=lane&15], C col=lane&15 row=(lane>>4)*4+reg.
__global__ __launch_bounds__(256, 4) void k_attn(const unsigned* __restrict__ mask,
    const unsigned short* __restrict__ WhT, const float* __restrict__ fs,
    const float* __restrict__ fd, const unsigned* __restrict__ gmax_u,
    float* __restrict__ acc_out, float* __restrict__ s_out){
  __shared__ unsigned short bslab[2][64*PADK];   // [buf][n][k]
  __shared__ float fslab[2][32];
  const int t = threadIdx.x, l = t & 63, wv = t >> 6;
  const int g = blockIdx.x & 127;        // 128 groups of 64 i-rows
  const int kchunk = blockIdx.x >> 7;    // 8 k-splits of 1024 j
  const int row = l & 15, quad = l >> 4;
  const int ibase = g*64 + wv*16;
  const int irow  = ibase + row;
  const float gmaxL = __uint_as_float(*gmax_u) - 64.0f;
  const float fsrL  = fs[irow];
  const float xL    = fsrL + gmaxL;
  const float mL    = fmaxf(xL, 0.2f*xL);  // row-max upper bound (leaky monotone)

  const unsigned jbase = (unsigned)kchunk*1024u;
  const unsigned m_off = (unsigned)irow*256u + (jbase >> 5);  // word per 32 j
  const unsigned sg_off = (unsigned)l*8192u + jbase + (unsigned)wv*8u;
  const int      sl_off = l*PADK + wv*8;
  const int      qsh    = quad*8;

  f32x4 acc[4];
  #pragma unroll
  for (int nb = 0; nb < 4; ++nb) acc[nb] = (f32x4){0.f,0.f,0.f,0.f};

  // prologue: stage step 0 into buf 0; prefetch mask words for steps 0,1
  {
    short8 v = *(const short8*)(WhT + sg_off);
    *(short8*)&bslab[0][sl_off] = v;
    if (t < 32) fslab[0][t] = fd[jbase + t];
  }
  unsigned m0 = mask[m_off + 0] >> qsh;
  unsigned m1 = mask[m_off + 1] >> qsh;

  float s0 = 0.f, s1 = 0.f;
  short8 nw; float nf = 0.f;

  #pragma unroll 1
  for (int s = 0; s < 32; s += 2){
    // ---- even sub-step: consume buf0/m0, stage s+1 -> buf1
    BAR();
    nw = *(const short8*)(WhT + sg_off + (s+1)*32);
    if (t < 32) nf = fd[jbase + (s+1)*32 + t];
    {
      f32x4 fv0 = *(const f32x4*)&fslab[0][qsh];
      f32x4 fv1 = *(const f32x4*)&fslab[0][qsh + 4];
      short8 w0 = *(const short8*)&bslab[0][( 0 + row)*PADK + qsh];
      short8 w1 = *(const short8*)&bslab[0][(16 + row)*PADK + qsh];
      short8 w2 = *(const short8*)&bslab[0][(32 + row)*PADK + qsh];
      short8 w3 = *(const short8*)&bslab[0][(48 + row)*PADK + qsh];
      attn_math(m0, fv0, fv1, w0, w1, w2, w3, fsrL, mL, acc, s0, s1);
    }
    if (s + 2 < 32) m0 = mask[m_off + s + 2] >> qsh;
    *(short8*)&bslab[1][sl_off] = nw;
    if (t < 32) fslab[1][t] = nf;

    // ---- odd sub-step: consume buf1/m1, stage s+2 -> buf0
    BAR();
    if (s + 2 < 32){
      nw = *(const short8*)(WhT + sg_off + (s+2)*32);
      if (t < 32) nf = fd[jbase + (s+2)*32 + t];
    }
    {
      f32x4 fv0 = *(const f32x4*)&fslab[1][qsh];
      f32x4 fv1 = *(const f32x4*)&fslab[1][qsh + 4];
      short8 w0 = *(const short8*)&bslab[1][( 0 + row)*PADK + qsh];
      short8 w1 = *(const short8*)&bslab[1][(16 + row)*PADK + qsh];
      short8 w2 = *(const short8*)&bslab[1][(32 + row)*PADK + qsh];
      short8 w3 = *(const short8*)&bslab[1][(48 + row)*PADK + qsh];
      attn_math(m1, fv0, fv1, w0, w1, w2, w3, fsrL, mL, acc, s0, s1);
    }
    if (s + 3 < 32) m1 = mask[m_off + s + 3] >> qsh;
    if (s + 2 < 32){
      *(short8*)&bslab[0][sl_off] = nw;
      if (t < 32) fslab[0][t] = nf;
    }
  }

  float sacc = s0 + s1;
  sacc += __shfl_xor(sacc, 16);
  sacc += __shfl_xor(sacc, 32);
  if (l < 16) s_out[kchunk*NN + ibase + l] = sacc;
  float* op = acc_out + ((size_t)kchunk*NN + ibase)*FOUT;
  #pragma unroll
  for (int nb = 0; nb < 4; ++nb)
    #pragma unroll
    for (int r = 0; r < 4; ++r)
      op[(quad*4 + r)*FOUT + nb*16 + row] = acc[nb][r];
}

// ---- k_out: combine 8 split-K partials, normalize, ELU.
__global__ __launch_bounds__(256) void k_out(const float* __restrict__ acc,
    const float* __restrict__ s, float* __restrict__ out){
  const int idx = blockIdx.x*256 + threadIdx.x;   // 524288 total
  const int i = idx >> 6;
  float num = 0.f, den = 0.f;
  #pragma unroll
  for (int ks = 0; ks < 8; ++ks){
    num += acc[idx + (size_t)ks*(NN*FOUT)];
    den += s[i + ks*NN];
  }
  float x = num / den;
  out[idx] = (x > 0.f) ? x : (__expf(x) - 1.0f);
}

extern "C" void kernel_launch(void* const* d_in, const int* in_sizes, int n_in,
                              void* d_out, int out_size, void* d_ws, size_t ws_size,
                              hipStream_t stream){
  const float* h   = (const float*)d_in[0];
  const int*   adj = (const int*)d_in[1];
  const float* W   = (const float*)d_in[2];
  const float* a   = (const float*)d_in[3];
  char* ws = (char*)d_ws;
  // ws: [0,1M) WhT | 1M fs | +32K fd | +64K gmax | [2M,18M) acc x8 |
  //     [20M,+256K) s x8 | [48M,56M) mask (2M words)
  unsigned short* WhT = (unsigned short*)ws;
  float*    fs     = (float*)(ws + (1u<<20));
  float*    fd     = (float*)(ws + (1u<<20) + 32768);
  unsigned* gmax_u = (unsigned*)(ws + (1u<<20) + 65536);
  float*    acc    = (float*)(ws + (2u<<20));
  float*    s_ws   = (float*)(ws + (20u<<20));
  unsigned* mask   = (unsigned*)(ws + (48u<<20));

  (void)hipMemsetAsync(gmax_u, 0, 4, stream);
  k_pm<<<3072, 256, 0, stream>>>(h, W, a, adj, WhT, fs, fd, gmax_u, mask);
  k_attn<<<1024, 256, 0, stream>>>(mask, WhT, fs, fd, gmax_u, acc, s_ws);
  k_out<<<2048, 256, 0, stream>>>(acc, s_ws, (float*)d_out);
}

// Round 13
// 444.586 us; speedup vs baseline: 1.1652x; 1.1149x over previous
//
#include <hip/hip_runtime.h>
#include <hip/hip_bf16.h>

#define NN 8192
#define FIN 256
#define FOUT 64
#define L2E 1.4426950408889634f
#define PADK 40   // LDS k-stride in shorts (32 data + 8 pad -> even bank spread)

typedef __attribute__((ext_vector_type(8))) short short8;
typedef __attribute__((ext_vector_type(4))) float f32x4;
typedef __attribute__((ext_vector_type(4))) int   iv4;

// Barrier with LDS-only drain: leaves vmcnt (global prefetch) in flight.
#define BAR() do { \
  __asm__ __volatile__("s_waitcnt lgkmcnt(0)" ::: "memory"); \
  __builtin_amdgcn_s_barrier(); \
  __asm__ __volatile__("" ::: "memory"); \
} while (0)

__device__ __forceinline__ unsigned short f2bf(float x){
  unsigned u = __float_as_uint(x);
  u += 0x7FFFu + ((u >> 16) & 1u);      // RTNE
  return (unsigned short)(u >> 16);
}

// spread4: deposit bit i of 8-bit x at bit 4i (verified: 0x02 -> 0x10).
__device__ __forceinline__ unsigned spread4(unsigned x){
  x &= 0xFFu;
  x = (x | (x << 12)) & 0x000F000Fu;
  x = (x | (x << 6))  & 0x03030303u;
  x = (x | (x << 3))  & 0x11111111u;
  return x;
}

// Convert one 1-KB group (256 j, lane l holds j = g*256 + 4l + c, c=0..3) to
// 8 mask words (j-order, identical layout to R12). All lanes redundantly
// compute word (l&7); lanes 0-7 store (one 32-B coalesced store).
__device__ __forceinline__ void cv_process(iv4 d, int l,
                                           unsigned* __restrict__ mp, int g){
  unsigned n = (unsigned)(d.x != 0)        | ((unsigned)(d.y != 0) << 1)
             | ((unsigned)(d.z != 0) << 2) | ((unsigned)(d.w != 0) << 3);
  unsigned long long B0 = __ballot((n & 1u) != 0);   // bit l <-> j = 4l+0
  unsigned long long B1 = __ballot((n & 2u) != 0);   // j = 4l+1
  unsigned long long B2 = __ballot((n & 4u) != 0);   // j = 4l+2
  unsigned long long B3 = __ballot((n & 8u) != 0);   // j = 4l+3
  const int hi = l & 4, sh = (l & 3) * 8;            // byte (l&7) of each u64
  unsigned b0 = (unsigned)((hi ? (B0 >> 32) : B0) >> sh);
  unsigned b1 = (unsigned)((hi ? (B1 >> 32) : B1) >> sh);
  unsigned b2 = (unsigned)((hi ? (B2 >> 32) : B2) >> sh);
  unsigned b3 = (unsigned)((hi ? (B3 >> 32) : B3) >> sh);
  unsigned word = spread4(b0) | (spread4(b1) << 1)
                | (spread4(b2) << 2) | (spread4(b3) << 3);
  if (l < 8) mp[g*8 + l] = word;   // word w covers j [g*256+w*32, +32)
}

// ---- k_pm: heterogeneous fused kernel, bid%3 interleave so BW-bound
// converter blocks co-schedule with VALU/LDS-bound prep blocks from t=0.
// Converter (R13): wave = one adj row, 32x 1-KB iv4 loads (m13 streaming
// shape), 8 KB in flight in named regs — replaces R12's 4-B/lane dword
// pattern that starved at 915 GB/s (MSHR-serialized, VALUBusy 7.6%).
__global__ __launch_bounds__(256) void k_pm(const float* __restrict__ h,
    const float* __restrict__ W, const float* __restrict__ a,
    const int* __restrict__ adj, unsigned short* __restrict__ WhT,
    float* __restrict__ fs, float* __restrict__ fd,
    unsigned* __restrict__ gmax_u, unsigned* __restrict__ mask){
  const int bid = blockIdx.x, t = threadIdx.x;
  const int l = t & 63, wv = t >> 6;
  if (bid % 3 == 0){
    const int pid = bid / 3;                // 0..1023
    __shared__ float Ws[128*64];   // 32 KB: half of W (k-tiled)
    __shared__ float hs[8][128];
    const int rb = pid * 8;                 // 8 rows per block, 2 per wave
    float acc0 = 0.f, acc1 = 0.f;
    for (int half = 0; half < 2; ++half){
      if (half) __syncthreads();
      for (int i = t; i < 2048; i += 256)
        ((float4*)Ws)[i] = ((const float4*)W)[half*2048 + i];
      {
        int rr = t >> 5, cc = t & 31;
        ((float4*)&hs[rr][0])[cc] =
            *(const float4*)(h + (size_t)(rb+rr)*FIN + half*128 + cc*4);
      }
      __syncthreads();
      #pragma unroll 8
      for (int k = 0; k < 128; ++k){
        float wval = Ws[k*64 + l];           // lane l = output feature
        acc0 = fmaf(hs[wv*2+0][k], wval, acc0);
        acc1 = fmaf(hs[wv*2+1][k], wval, acc1);
      }
    }
    const int r0 = rb + wv*2, r1 = r0 + 1;
    float a1 = a[l], a2 = a[64 + l];
    float p0 = acc0*a1, q0 = acc0*a2, p1 = acc1*a1, q1 = acc1*a2;
    #pragma unroll
    for (int m = 1; m < 64; m <<= 1){
      p0 += __shfl_xor(p0, m); q0 += __shfl_xor(q0, m);
      p1 += __shfl_xor(p1, m); q1 += __shfl_xor(q1, m);
    }
    if (l == 0){
      fs[r0] = p0*L2E; fs[r1] = p1*L2E; fd[r0] = q0*L2E; fd[r1] = q1*L2E;
      atomicMax(gmax_u, __float_as_uint(q0*L2E + 64.0f));
      atomicMax(gmax_u, __float_as_uint(q1*L2E + 64.0f));
    }
    WhT[(size_t)l*NN + r0] = f2bf(acc0);
    WhT[(size_t)l*NN + r1] = f2bf(acc1);
  } else {
    const int cid = bid - bid/3 - 1;        // 0..2047
    const unsigned rowid = (unsigned)cid*4u + (unsigned)wv;  // 0..8191
    const iv4* __restrict__ ap = (const iv4*)(adj + (size_t)rowid*8192u) + l;
    unsigned* __restrict__ mp = mask + rowid*256u;
    // 32 groups of 256 j; 8 x 1-KB loads in flight (named regs, 8 KB/wave)
    iv4 d0 = ap[0*64], d1 = ap[1*64], d2 = ap[2*64], d3 = ap[3*64];
    iv4 d4 = ap[4*64], d5 = ap[5*64], d6 = ap[6*64], d7 = ap[7*64];
    #pragma unroll 1
    for (int i = 0; i < 32; i += 8){
      cv_process(d0, l, mp, i+0); if (i+ 8 < 32) d0 = ap[(i+ 8)*64];
      cv_process(d1, l, mp, i+1); if (i+ 9 < 32) d1 = ap[(i+ 9)*64];
      cv_process(d2, l, mp, i+2); if (i+10 < 32) d2 = ap[(i+10)*64];
      cv_process(d3, l, mp, i+3); if (i+11 < 32) d3 = ap[(i+11)*64];
      cv_process(d4, l, mp, i+4); if (i+12 < 32) d4 = ap[(i+12)*64];
      cv_process(d5, l, mp, i+5); if (i+13 < 32) d5 = ap[(i+13)*64];
      cv_process(d6, l, mp, i+6); if (i+14 < 32) d6 = ap[(i+14)*64];
      cv_process(d7, l, mp, i+7); if (i+15 < 32) d7 = ap[(i+15)*64];
    }
  }
}

// ---- k_attn (R10/R12-verified, unchanged): block = 64 i-rows x 1024-j kchunk.
// WhT+fd staged in LDS; adj via bitmask (1 word / 32 j, L2-resident).
__device__ __forceinline__ void attn_math(unsigned mbits, f32x4 fv0, f32x4 fv1,
    short8 w0, short8 w1, short8 w2, short8 w3,
    float fsrL, float mL, f32x4* acc, float& s0, float& s1){
  const float fv[8] = {fv0[0],fv0[1],fv0[2],fv0[3], fv1[0],fv1[1],fv1[2],fv1[3]};
  float w[8];
  #pragma unroll
  for (int j = 0; j < 8; ++j){
    float x  = fsrL + fv[j];                      // log2 domain
    float tt = fmaxf(x, 0.2f*x);                  // leaky_relu (scale-invariant)
    float e  = __builtin_amdgcn_exp2f(tt - mL);   // v_exp_f32
    w[j] = (mbits & (1u << j)) ? e : 0.0f;        // adj bit
  }
  s0 += (w[0]+w[2]) + (w[4]+w[6]);
  s1 += (w[1]+w[3]) + (w[5]+w[7]);
  short8 af;
  __hip_bfloat162* afp = (__hip_bfloat162*)&af;
  #pragma unroll
  for (int j = 0; j < 4; ++j)
    afp[j] = __float22bfloat162_rn(make_float2(w[2*j], w[2*j+1]));  // v_cvt_pk_bf16_f32
  acc[0] = __builtin_amdgcn_mfma_f32_16x16x32_bf16(af, w0, acc[0], 0,0,0);
  acc[1] = __builtin_amdgcn_mfma_f32_16x16x32_bf16(af, w1, acc[1], 0,0,0);
  acc[2] = __builtin_amdgcn_mfma_f32_16x16x32_bf16(af, w2, acc[2], 0,0,0);
  acc[3] = __builtin_amdgcn_mfma_f32_16x16x32_bf16(af, w3, acc[3], 0,0,0);
}

// Verified layouts (m89/m120): A[m=lane&15][k=(lane>>4)*8+j],
// B[k=(lane>>4)*8+j][n=lane&15], C col=lane&15 row=(lane>>4)*4+reg.
__global__ __launch_bounds__(256, 4) void k_attn(const unsigned* __restrict__ mask,
    const unsigned short* __restrict__ WhT, const float* __restrict__ fs,
    const float* __restrict__ fd, const unsigned* __restrict__ gmax_u,
    float* __restrict__ acc_out, float* __restrict__ s_out){
  __shared__ unsigned short bslab[2][64*PADK];   // [buf][n][k]
  __shared__ float fslab[2][32];
  const int t = threadIdx.x, l = t & 63, wv = t >> 6;
  const int g = blockIdx.x & 127;        // 128 groups of 64 i-rows
  const int kchunk = blockIdx.x >> 7;    // 8 k-splits of 1024 j
  const int row = l & 15, quad = l >> 4;
  const int ibase = g*64 + wv*16;
  const int irow  = ibase + row;
  const float gmaxL = __uint_as_float(*gmax_u) - 64.0f;
  const float fsrL  = fs[irow];
  const float xL    = fsrL + gmaxL;
  const float mL    = fmaxf(xL, 0.2f*xL);  // row-max upper bound (leaky monotone)

  const unsigned jbase = (unsigned)kchunk*1024u;
  const unsigned m_off = (unsigned)irow*256u + (jbase >> 5);  // word per 32 j
  const unsigned sg_off = (unsigned)l*8192u + jbase + (unsigned)wv*8u;
  const int      sl_off = l*PADK + wv*8;
  const int      qsh    = quad*8;

  f32x4 acc[4];
  #pragma unroll
  for (int nb = 0; nb < 4; ++nb) acc[nb] = (f32x4){0.f,0.f,0.f,0.f};

  // prologue: stage step 0 into buf 0; prefetch mask words for steps 0,1
  {
    short8 v = *(const short8*)(WhT + sg_off);
    *(short8*)&bslab[0][sl_off] = v;
    if (t < 32) fslab[0][t] = fd[jbase + t];
  }
  unsigned m0 = mask[m_off + 0] >> qsh;
  unsigned m1 = mask[m_off + 1] >> qsh;

  float s0 = 0.f, s1 = 0.f;
  short8 nw; float nf = 0.f;

  #pragma unroll 1
  for (int s = 0; s < 32; s += 2){
    // ---- even sub-step: consume buf0/m0, stage s+1 -> buf1
    BAR();
    nw = *(const short8*)(WhT + sg_off + (s+1)*32);
    if (t < 32) nf = fd[jbase + (s+1)*32 + t];
    {
      f32x4 fv0 = *(const f32x4*)&fslab[0][qsh];
      f32x4 fv1 = *(const f32x4*)&fslab[0][qsh + 4];
      short8 w0 = *(const short8*)&bslab[0][( 0 + row)*PADK + qsh];
      short8 w1 = *(const short8*)&bslab[0][(16 + row)*PADK + qsh];
      short8 w2 = *(const short8*)&bslab[0][(32 + row)*PADK + qsh];
      short8 w3 = *(const short8*)&bslab[0][(48 + row)*PADK + qsh];
      attn_math(m0, fv0, fv1, w0, w1, w2, w3, fsrL, mL, acc, s0, s1);
    }
    if (s + 2 < 32) m0 = mask[m_off + s + 2] >> qsh;
    *(short8*)&bslab[1][sl_off] = nw;
    if (t < 32) fslab[1][t] = nf;

    // ---- odd sub-step: consume buf1/m1, stage s+2 -> buf0
    BAR();
    if (s + 2 < 32){
      nw = *(const short8*)(WhT + sg_off + (s+2)*32);
      if (t < 32) nf = fd[jbase + (s+2)*32 + t];
    }
    {
      f32x4 fv0 = *(const f32x4*)&fslab[1][qsh];
      f32x4 fv1 = *(const f32x4*)&fslab[1][qsh + 4];
      short8 w0 = *(const short8*)&bslab[1][( 0 + row)*PADK + qsh];
      short8 w1 = *(const short8*)&bslab[1][(16 + row)*PADK + qsh];
      short8 w2 = *(const short8*)&bslab[1][(32 + row)*PADK + qsh];
      short8 w3 = *(const short8*)&bslab[1][(48 + row)*PADK + qsh];
      attn_math(m1, fv0, fv1, w0, w1, w2, w3, fsrL, mL, acc, s0, s1);
    }
    if (s + 3 < 32) m1 = mask[m_off + s + 3] >> qsh;
    if (s + 2 < 32){
      *(short8*)&bslab[0][sl_off] = nw;
      if (t < 32) fslab[0][t] = nf;
    }
  }

  float sacc = s0 + s1;
  sacc += __shfl_xor(sacc, 16);
  sacc += __shfl_xor(sacc, 32);
  if (l < 16) s_out[kchunk*NN + ibase + l] = sacc;
  float* op = acc_out + ((size_t)kchunk*NN + ibase)*FOUT;
  #pragma unroll
  for (int nb = 0; nb < 4; ++nb)
    #pragma unroll
    for (int r = 0; r < 4; ++r)
      op[(quad*4 + r)*FOUT + nb*16 + row] = acc[nb][r];
}

// ---- k_out: combine 8 split-K partials, normalize, ELU.
__global__ __launch_bounds__(256) void k_out(const float* __restrict__ acc,
    const float* __restrict__ s, float* __restrict__ out){
  const int idx = blockIdx.x*256 + threadIdx.x;   // 524288 total
  const int i = idx >> 6;
  float num = 0.f, den = 0.f;
  #pragma unroll
  for (int ks = 0; ks < 8; ++ks){
    num += acc[idx + (size_t)ks*(NN*FOUT)];
    den += s[i + ks*NN];
  }
  float x = num / den;
  out[idx] = (x > 0.f) ? x : (__expf(x) - 1.0f);
}

extern "C" void kernel_launch(void* const* d_in, const int* in_sizes, int n_in,
                              void* d_out, int out_size, void* d_ws, size_t ws_size,
                              hipStream_t stream){
  const float* h   = (const float*)d_in[0];
  const int*   adj = (const int*)d_in[1];
  const float* W   = (const float*)d_in[2];
  const float* a   = (const float*)d_in[3];
  char* ws = (char*)d_ws;
  // ws: [0,1M) WhT | 1M fs | +32K fd | +64K gmax | [2M,18M) acc x8 |
  //     [20M,+256K) s x8 | [48M,56M) mask (2M words)
  unsigned short* WhT = (unsigned short*)ws;
  float*    fs     = (float*)(ws + (1u<<20));
  float*    fd     = (float*)(ws + (1u<<20) + 32768);
  unsigned* gmax_u = (unsigned*)(ws + (1u<<20) + 65536);
  float*    acc    = (float*)(ws + (2u<<20));
  float*    s_ws   = (float*)(ws + (20u<<20));
  unsigned* mask   = (unsigned*)(ws + (48u<<20));

  (void)hipMemsetAsync(gmax_u, 0, 4, stream);
  k_pm<<<3072, 256, 0, stream>>>(h, W, a, adj, WhT, fs, fd, gmax_u, mask);
  k_attn<<<1024, 256, 0, stream>>>(mask, WhT, fs, fd, gmax_u, acc, s_ws);
  k_out<<<2048, 256, 0, stream>>>(acc, s_ws, (float*)d_out);
}